// Round 11
// baseline (352.758 us; speedup 1.0000x reference)
//
#include <hip/hip_runtime.h>
#include <hip/hip_fp16.h>

#define D 64
#define EPS 1e-5f

// CSR bucketing params: buckets of 512 consecutive dst nodes
#define BK_SHIFT 9
#define BK_W 512
#define NBMAX 256        // supports n up to 131072
#define BK_CAP 8192      // bucket pair-slab capacity
#define CHUNK 8192       // edges per bucket_k block
#define ELL_W 16         // ELL width (first 16 edges per node)
#define SP_CAP 4096      // per-bucket spill capacity (ints)

// ---------------- Phase A: bucketize edges; pack (src<<9 | dst_local) ----------------

__global__ __launch_bounds__(256) void bucket_k(const int* __restrict__ src,
                                                const int* __restrict__ dst,
                                                int* __restrict__ bcnt,
                                                int* __restrict__ pairs,
                                                int e, int nbk) {
  __shared__ int hcnt[NBMAX];
  __shared__ int hbase[NBMAX];
  const int t = threadIdx.x;
  const int e0 = blockIdx.x * CHUNK;
  const int e1 = min(e0 + CHUNK, e);
  for (int i = t; i < nbk; i += 256) hcnt[i] = 0;
  __syncthreads();
  for (int i = e0 + t; i < e1; i += 256)
    atomicAdd(&hcnt[dst[i] >> BK_SHIFT], 1);
  __syncthreads();
  for (int i = t; i < nbk; i += 256) {
    int c = hcnt[i];
    hbase[i] = c ? atomicAdd(&bcnt[i], c) : 0;
    hcnt[i] = 0;   // reuse as cursor
  }
  __syncthreads();
  for (int i = e0 + t; i < e1; i += 256) {
    int s = src[i], d = dst[i];
    int b = d >> BK_SHIFT;
    int r = hbase[b] + atomicAdd(&hcnt[b], 1);
    if (r < BK_CAP) pairs[(size_t)b * BK_CAP + r] = (s << BK_SHIFT) | (d & (BK_W - 1));
  }
}

// ---------------- Fused CSR->ELL+spill ----------------
// ell[node*16 + r] holds edge r (<16) of node; pad slots hold index n (zero row).
// Spill (deg>16) per node padded to x16 in per-bucket slab; rpdeg = (spill_base, deg).
// Zero-row padding => agg needs NO predication anywhere.

__global__ __launch_bounds__(256) void bucket2csr_k(const int* __restrict__ bcnt,
                                                    const int* __restrict__ pairs,
                                                    int2* __restrict__ rpdeg,
                                                    float* __restrict__ dis,
                                                    int* __restrict__ ell,
                                                    int* __restrict__ spill, int n) {
  __shared__ int h[BK_W];          // deg per local node
  __shared__ int cur[BK_W];        // placement cursors
  __shared__ int sbase[BK_W];      // per-node spill base (local)
  __shared__ int s1[256], s2[256];
  __shared__ int ellst[BK_W * ELL_W];  // 8192 ints
  __shared__ int spst[SP_CAP];         // 4096 ints
  const int b = blockIdx.x, t = threadIdx.x;
  const int base = b << BK_SHIFT;
  const int m = min(bcnt[b], BK_CAP);

  h[t] = 0; h[t + 256] = 0;
  cur[t] = 0; cur[t + 256] = 0;
  for (int i = t; i < BK_W * ELL_W; i += 256) ellst[i] = n;   // pad = zero row
  for (int i = t; i < SP_CAP; i += 256) spst[i] = n;
  __syncthreads();
  const int* p = pairs + (size_t)b * BK_CAP;
  for (int i = t; i < m; i += 256) atomicAdd(&h[p[i] & (BK_W - 1)], 1);
  __syncthreads();

  // spill counts padded to x16 so agg tail batches never cross nodes
  const int sc1 = (max(h[t] - ELL_W, 0) + 15) & ~15;
  const int sc2 = (max(h[t + 256] - ELL_W, 0) + 15) & ~15;
  s1[t] = sc1; s2[t] = sc2;
  __syncthreads();
  for (int off = 1; off < 256; off <<= 1) {
    int x1 = (t >= off) ? s1[t - off] : 0;
    int x2 = (t >= off) ? s2[t - off] : 0;
    __syncthreads();
    s1[t] += x1; s2[t] += x2;
    __syncthreads();
  }
  const int tot1 = s1[255];
  const int sptot = tot1 + s2[255];
  sbase[t]       = s1[t] - sc1;
  sbase[t + 256] = tot1 + s2[t] - sc2;
  {
    int n1 = base + t, n2 = base + t + 256;
    if (n1 < n) { rpdeg[n1] = make_int2(b * SP_CAP + sbase[t], h[t]);
                  dis[n1] = rsqrtf((float)h[t] + 1.0f); }
    if (n2 < n) { rpdeg[n2] = make_int2(b * SP_CAP + sbase[t + 256], h[t + 256]);
                  dis[n2] = rsqrtf((float)h[t + 256] + 1.0f); }
  }
  __syncthreads();

  for (int i = t; i < m; i += 256) {
    int pk = p[i];
    int loc = pk & (BK_W - 1);
    int r = atomicAdd(&cur[loc], 1);
    int s = pk >> BK_SHIFT;
    if (r < ELL_W) ellst[loc * ELL_W + r] = s;
    else {
      int sp = sbase[loc] + (r - ELL_W);
      if (sp < SP_CAP) spst[sp] = s;
    }
  }
  __syncthreads();
  for (int i = t; i < BK_W * ELL_W; i += 256) ell[(size_t)b * BK_W * ELL_W + i] = ellst[i];
  const int spout = min(sptot, SP_CAP);
  for (int i = t; i < spout; i += 256) spill[(size_t)b * SP_CAP + i] = spst[i];
}

// ---------------- BN/bias folding ----------------

__global__ void bnprep_k(const float* __restrict__ b1, const float* __restrict__ b2,
                         const float* __restrict__ b3,
                         const float* __restrict__ g1, const float* __restrict__ be1,
                         const float* __restrict__ rm1, const float* __restrict__ rv1,
                         const float* __restrict__ g2, const float* __restrict__ be2,
                         const float* __restrict__ rm2, const float* __restrict__ rv2,
                         float* __restrict__ scsh) {
  int t = threadIdx.x;
  int j = t & 63, l = t >> 6;
  float sc, sh;
  if (l == 0)      { sc = g1[j] * rsqrtf(rv1[j] + EPS); sh = (b1[j] - rm1[j]) * sc + be1[j]; }
  else if (l == 1) { sc = g2[j] * rsqrtf(rv2[j] + EPS); sh = (b2[j] - rm2[j]) * sc + be2[j]; }
  else             { sc = 1.0f;                          sh = b3[j]; }
  scsh[l * 128 + j] = sc;
  scsh[l * 128 + 64 + j] = sh;
}

// ---------------- GEMM: out[r] = dis[r] * (in[r] @ W), fp16 out, fp32/fp16 in --------

#define GT_R 128
#define XT_LD 132

__device__ inline float ld1(const float* p)  { return *p; }
__device__ inline float ld1(const __half* p) { return __half2float(*p); }

template <typename InT>
__global__ __launch_bounds__(256) void gemm_k(const InT* __restrict__ in,
                                              const float* __restrict__ W,
                                              const float* __restrict__ dis,
                                              __half* __restrict__ out, int nrows) {
  __shared__ float ws[64 * 64];
  __shared__ float xt[64 * XT_LD];
  __shared__ float dtile[GT_R];

  const int t    = threadIdx.x;
  const int lane = t & 63;
  const int w    = t >> 6;
  const int row0 = blockIdx.x * GT_R;

  for (int i = t; i < 1024; i += 256)
    ((float4*)ws)[i] = ((const float4*)W)[i];

  if (t < GT_R) {
    int r = row0 + t;
    dtile[t] = (r < nrows) ? dis[r] : 0.f;
  }

#pragma unroll
  for (int j = 0; j < 8; ++j) {
    int Q = w + 4 * j;
    int r = row0 + 4 * Q;
    float4 v;
    v.x = (r + 0 < nrows) ? ld1(&in[(size_t)(r + 0) * D + lane]) : 0.f;
    v.y = (r + 1 < nrows) ? ld1(&in[(size_t)(r + 1) * D + lane]) : 0.f;
    v.z = (r + 2 < nrows) ? ld1(&in[(size_t)(r + 2) * D + lane]) : 0.f;
    v.w = (r + 3 < nrows) ? ld1(&in[(size_t)(r + 3) * D + lane]) : 0.f;
    *(float4*)&xt[lane * XT_LD + 4 * Q] = v;
  }
  __syncthreads();

  const int cq = (t & 15) * 4;
  const int rg = (t >> 4) * 8;
  float acc[8][4] = {};

#pragma unroll 4
  for (int k = 0; k < 64; ++k) {
    float4 b   = *(const float4*)&ws[k * 64 + cq];
    float4 alo = *(const float4*)&xt[k * XT_LD + rg];
    float4 ahi = *(const float4*)&xt[k * XT_LD + rg + 4];
    const float ar[8] = {alo.x, alo.y, alo.z, alo.w, ahi.x, ahi.y, ahi.z, ahi.w};
#pragma unroll
    for (int i = 0; i < 8; ++i) {
      acc[i][0] = fmaf(ar[i], b.x, acc[i][0]);
      acc[i][1] = fmaf(ar[i], b.y, acc[i][1]);
      acc[i][2] = fmaf(ar[i], b.z, acc[i][2]);
      acc[i][3] = fmaf(ar[i], b.w, acc[i][3]);
    }
  }

#pragma unroll
  for (int i = 0; i < 8; ++i) {
    int r = row0 + rg + i;
    if (r < nrows) {
      float dsc = dtile[rg + i];
      union { __half2 h[2]; float2 f; } u;
      u.h[0] = __floats2half2_rn(dsc * acc[i][0], dsc * acc[i][1]);
      u.h[1] = __floats2half2_rn(dsc * acc[i][2], dsc * acc[i][3]);
      *(float2*)&out[(size_t)r * D + cq] = u.f;
    }
  }
}

// ---------------- Aggregation: 2 nodes/wave, ELL direct addressing, no predication --
// ell address computable from node id -> index loads issue with NO rpdeg dependency.
// Pad indices point at zero row n of h2s -> adds are exact zeros, no cndmask.
// Spill tail (deg>16, wave-uniform branch) reads padded x16 slab, also unpredicated.

template <bool RELU, typename OutT>
__global__ __launch_bounds__(256) void agg_k(const __half* __restrict__ h2s,
                                             const int2* __restrict__ rpdeg,
                                             const int* __restrict__ ell,
                                             const int* __restrict__ spill,
                                             const float* __restrict__ dis,
                                             const float* __restrict__ scsh,
                                             OutT* __restrict__ out, int n) {
  const int lane = threadIdx.x & 63;
  const int wv   = (blockIdx.x * blockDim.x + threadIdx.x) >> 6;
  const int n0   = __builtin_amdgcn_readfirstlane(wv * 2);
  if (n0 >= n) return;
  const bool v1 = (n0 + 1 < n);
  const int n1  = v1 ? n0 + 1 : n0;
  const int g  = lane >> 4;
  const int sl = lane & 15;
  const int jb = 4 * g;
  const uint2* __restrict__ h2v = (const uint2*)h2s;   // row = 16 x uint2

  // ELL indices: addresses independent of any prior load -> issue immediately
  const int4 cc0 = *(const int4*)&ell[(size_t)n0 * ELL_W + jb];
  const int4 cc1 = *(const int4*)&ell[(size_t)n1 * ELL_W + jb];
  const int4 rdp = *(const int4*)&rpdeg[n0];           // concurrent with cc0/cc1
  const int p0s = rdp.x, deg0 = rdp.y, p1s = rdp.z, deg1 = rdp.w;
  const uint2 self0 = h2v[(size_t)n0 * 16 + sl];
  const uint2 self1 = h2v[(size_t)n1 * 16 + sl];

  const __half2 zero2 = __floats2half2_rn(0.f, 0.f);
  __half2 A0 = zero2, A1 = zero2, B0 = zero2, B1 = zero2;
  __half2 C0 = zero2, C1 = zero2, D0 = zero2, D1 = zero2;   // node0
  __half2 E0 = zero2, E1 = zero2, F0 = zero2, F1 = zero2;
  __half2 G0 = zero2, G1 = zero2, H0 = zero2, H1 = zero2;   // node1

  {  // ELL batch, both nodes, fully unpredicated
    const uint2 r0 = h2v[(size_t)cc0.x * 16 + sl];
    const uint2 r1 = h2v[(size_t)cc0.y * 16 + sl];
    const uint2 r2 = h2v[(size_t)cc0.z * 16 + sl];
    const uint2 r3 = h2v[(size_t)cc0.w * 16 + sl];
    const uint2 q0 = h2v[(size_t)cc1.x * 16 + sl];
    const uint2 q1 = h2v[(size_t)cc1.y * 16 + sl];
    const uint2 q2 = h2v[(size_t)cc1.z * 16 + sl];
    const uint2 q3 = h2v[(size_t)cc1.w * 16 + sl];
    A0 = __hadd2(A0, *(const __half2*)&r0.x); A1 = __hadd2(A1, *(const __half2*)&r0.y);
    B0 = __hadd2(B0, *(const __half2*)&r1.x); B1 = __hadd2(B1, *(const __half2*)&r1.y);
    C0 = __hadd2(C0, *(const __half2*)&r2.x); C1 = __hadd2(C1, *(const __half2*)&r2.y);
    D0 = __hadd2(D0, *(const __half2*)&r3.x); D1 = __hadd2(D1, *(const __half2*)&r3.y);
    E0 = __hadd2(E0, *(const __half2*)&q0.x); E1 = __hadd2(E1, *(const __half2*)&q0.y);
    F0 = __hadd2(F0, *(const __half2*)&q1.x); F1 = __hadd2(F1, *(const __half2*)&q1.y);
    G0 = __hadd2(G0, *(const __half2*)&q2.x); G1 = __hadd2(G1, *(const __half2*)&q2.y);
    H0 = __hadd2(H0, *(const __half2*)&q3.x); H1 = __hadd2(H1, *(const __half2*)&q3.y);
  }

  // spill tails (deg > 16; per-node x16-padded regions, pad index = n)
  for (int e = 0; e < deg0 - ELL_W; e += 16) {
    const int4 cc = *(const int4*)&spill[p0s + e + jb];
    const uint2 r0 = h2v[(size_t)cc.x * 16 + sl];
    const uint2 r1 = h2v[(size_t)cc.y * 16 + sl];
    const uint2 r2 = h2v[(size_t)cc.z * 16 + sl];
    const uint2 r3 = h2v[(size_t)cc.w * 16 + sl];
    A0 = __hadd2(A0, *(const __half2*)&r0.x); A1 = __hadd2(A1, *(const __half2*)&r0.y);
    B0 = __hadd2(B0, *(const __half2*)&r1.x); B1 = __hadd2(B1, *(const __half2*)&r1.y);
    C0 = __hadd2(C0, *(const __half2*)&r2.x); C1 = __hadd2(C1, *(const __half2*)&r2.y);
    D0 = __hadd2(D0, *(const __half2*)&r3.x); D1 = __hadd2(D1, *(const __half2*)&r3.y);
  }
  for (int e = 0; e < deg1 - ELL_W; e += 16) {
    const int4 cc = *(const int4*)&spill[p1s + e + jb];
    const uint2 q0 = h2v[(size_t)cc.x * 16 + sl];
    const uint2 q1 = h2v[(size_t)cc.y * 16 + sl];
    const uint2 q2 = h2v[(size_t)cc.z * 16 + sl];
    const uint2 q3 = h2v[(size_t)cc.w * 16 + sl];
    E0 = __hadd2(E0, *(const __half2*)&q0.x); E1 = __hadd2(E1, *(const __half2*)&q0.y);
    F0 = __hadd2(F0, *(const __half2*)&q1.x); F1 = __hadd2(F1, *(const __half2*)&q1.y);
    G0 = __hadd2(G0, *(const __half2*)&q2.x); G1 = __hadd2(G1, *(const __half2*)&q2.y);
    H0 = __hadd2(H0, *(const __half2*)&q3.x); H1 = __hadd2(H1, *(const __half2*)&q3.y);
  }

  const float di0 = dis[n0];
  const float di1 = dis[n1];
  const float4 sc = *(const float4*)&scsh[4 * sl];
  const float4 sh = *(const float4*)&scsh[64 + 4 * sl];

  // ---- node0 combine/reduce/store ----
  {
    const float2 a0 = __half22float2(A0), a1 = __half22float2(A1);
    const float2 b0 = __half22float2(B0), b1 = __half22float2(B1);
    const float2 c0 = __half22float2(C0), c1 = __half22float2(C1);
    const float2 d0 = __half22float2(D0), d1 = __half22float2(D1);
    float2 s0f = __half22float2(*(const __half2*)&self0.x);
    float2 s1f = __half22float2(*(const __half2*)&self0.y);
    float r0 = ((a0.x + b0.x) + (c0.x + d0.x)) + (g == 0 ? s0f.x : 0.f);
    float r1 = ((a0.y + b0.y) + (c0.y + d0.y)) + (g == 0 ? s0f.y : 0.f);
    float r2 = ((a1.x + b1.x) + (c1.x + d1.x)) + (g == 0 ? s1f.x : 0.f);
    float r3 = ((a1.y + b1.y) + (c1.y + d1.y)) + (g == 0 ? s1f.y : 0.f);
    r0 += __shfl_xor(r0, 16, 64); r1 += __shfl_xor(r1, 16, 64);
    r2 += __shfl_xor(r2, 16, 64); r3 += __shfl_xor(r3, 16, 64);
    r0 += __shfl_xor(r0, 32, 64); r1 += __shfl_xor(r1, 32, 64);
    r2 += __shfl_xor(r2, 32, 64); r3 += __shfl_xor(r3, 32, 64);
    float o0 = fmaf(di0 * r0, sc.x, sh.x);
    float o1 = fmaf(di0 * r1, sc.y, sh.y);
    float o2 = fmaf(di0 * r2, sc.z, sh.z);
    float o3 = fmaf(di0 * r3, sc.w, sh.w);
    if (RELU) {
      o0 = fmaxf(o0, 0.f); o1 = fmaxf(o1, 0.f);
      o2 = fmaxf(o2, 0.f); o3 = fmaxf(o3, 0.f);
    }
    if (g == 0) {
      if constexpr (sizeof(OutT) == 2) {
        union { __half2 h[2]; uint2 u; } v;
        v.h[0] = __floats2half2_rn(o0, o1);
        v.h[1] = __floats2half2_rn(o2, o3);
        *(uint2*)&out[(size_t)n0 * D + 4 * sl] = v.u;
      } else {
        *(float4*)&out[(size_t)n0 * D + 4 * sl] = make_float4(o0, o1, o2, o3);
      }
    }
  }
  // ---- node1 combine/reduce/store ----
  {
    const float2 a0 = __half22float2(E0), a1 = __half22float2(E1);
    const float2 b0 = __half22float2(F0), b1 = __half22float2(F1);
    const float2 c0 = __half22float2(G0), c1 = __half22float2(G1);
    const float2 d0 = __half22float2(H0), d1 = __half22float2(H1);
    float2 s0f = __half22float2(*(const __half2*)&self1.x);
    float2 s1f = __half22float2(*(const __half2*)&self1.y);
    float r0 = ((a0.x + b0.x) + (c0.x + d0.x)) + (g == 0 ? s0f.x : 0.f);
    float r1 = ((a0.y + b0.y) + (c0.y + d0.y)) + (g == 0 ? s0f.y : 0.f);
    float r2 = ((a1.x + b1.x) + (c1.x + d1.x)) + (g == 0 ? s1f.x : 0.f);
    float r3 = ((a1.y + b1.y) + (c1.y + d1.y)) + (g == 0 ? s1f.y : 0.f);
    r0 += __shfl_xor(r0, 16, 64); r1 += __shfl_xor(r1, 16, 64);
    r2 += __shfl_xor(r2, 16, 64); r3 += __shfl_xor(r3, 16, 64);
    r0 += __shfl_xor(r0, 32, 64); r1 += __shfl_xor(r1, 32, 64);
    r2 += __shfl_xor(r2, 32, 64); r3 += __shfl_xor(r3, 32, 64);
    float o0 = fmaf(di1 * r0, sc.x, sh.x);
    float o1 = fmaf(di1 * r1, sc.y, sh.y);
    float o2 = fmaf(di1 * r2, sc.z, sh.z);
    float o3 = fmaf(di1 * r3, sc.w, sh.w);
    if (RELU) {
      o0 = fmaxf(o0, 0.f); o1 = fmaxf(o1, 0.f);
      o2 = fmaxf(o2, 0.f); o3 = fmaxf(o3, 0.f);
    }
    if (g == 0 && v1) {
      if constexpr (sizeof(OutT) == 2) {
        union { __half2 h[2]; uint2 u; } v;
        v.h[0] = __floats2half2_rn(o0, o1);
        v.h[1] = __floats2half2_rn(o2, o3);
        *(uint2*)&out[(size_t)n1 * D + 4 * sl] = v.u;
      } else {
        *(float4*)&out[(size_t)n1 * D + 4 * sl] = make_float4(o0, o1, o2, o3);
      }
    }
  }
}

// ---------------- Global mean pool (batch is sorted) ----------------

__global__ __launch_bounds__(256) void pool_k(const float* __restrict__ h,
                                              const int* __restrict__ batch,
                                              float* __restrict__ psum,
                                              float* __restrict__ pcnt, int n) {
  int lane  = threadIdx.x & 63;
  int wid   = __builtin_amdgcn_readfirstlane((blockIdx.x * blockDim.x + threadIdx.x) >> 6);
  int start = wid * 64;
  if (start >= n) return;
  int end = min(start + 64, n);
  int cur = batch[start];
  float sum = 0.f;
  int run = 0;
  for (int i = start; i < end; ++i) {
    int g = batch[i];
    if (g != cur) {
      atomicAdd(&psum[cur * D + lane], sum);
      if (lane == 0) atomicAdd(&pcnt[cur], (float)run);
      sum = 0.f; run = 0; cur = g;
    }
    sum += h[(size_t)i * D + lane];
    run += 1;
  }
  atomicAdd(&psum[cur * D + lane], sum);
  if (lane == 0) atomicAdd(&pcnt[cur], (float)run);
}

__global__ void pooldiv_k(const float* __restrict__ psum, const float* __restrict__ pcnt,
                          float* __restrict__ hg) {
  int t = blockIdx.x * blockDim.x + threadIdx.x;
  if (t < 64 * D) hg[t] = psum[t] / fmaxf(pcnt[t >> 6], 1.0f);
}

// ---------------- launcher ----------------

extern "C" void kernel_launch(void* const* d_in, const int* in_sizes, int n_in,
                              void* d_out, int out_size, void* d_ws, size_t ws_size,
                              hipStream_t stream) {
  const float* x   = (const float*)d_in[0];
  const int*   ei  = (const int*)d_in[1];
  const int*   bat = (const int*)d_in[2];
  const float* W1  = (const float*)d_in[3];
  const float* W2  = (const float*)d_in[4];
  const float* W3  = (const float*)d_in[5];
  const float* b1  = (const float*)d_in[6];
  const float* b2  = (const float*)d_in[7];
  const float* b3  = (const float*)d_in[8];
  const float* g1  = (const float*)d_in[9];
  const float* be1 = (const float*)d_in[10];
  const float* rm1 = (const float*)d_in[11];
  const float* rv1 = (const float*)d_in[12];
  const float* g2  = (const float*)d_in[13];
  const float* be2 = (const float*)d_in[14];
  const float* rm2 = (const float*)d_in[15];
  const float* rv2 = (const float*)d_in[16];

  const int n = in_sizes[0] / D;   // 100000
  const int e = in_sizes[1] / 2;   // 1200000
  const int* src = ei;
  const int* dst = ei + e;
  const int nbk = (n + BK_W - 1) >> BK_SHIFT;   // 196

  char* ws = (char*)d_ws;
  size_t off = 0;
  auto alloc = [&](size_t bytes) -> void* {
    void* p = ws + off;
    off = (off + bytes + 255) & ~(size_t)255;
    return p;
  };
  __half* buf16 = (__half*)alloc((size_t)n * D * 2);        // agg fp16 out (layers 1,2)
  int*    pairs = (int*)alloc((size_t)NBMAX * BK_CAP * 4);  // bucket pair slabs
  __half* hbuf  = (__half*)alloc((size_t)(n + 1) * D * 2);  // gemm fp16 out + zero row n
  int2*   rpdeg = (int2*)alloc((size_t)(n + 1) * 8);
  float*  dis   = (float*)alloc((size_t)n * 4);
  int*    ell   = (int*)alloc((size_t)nbk * BK_W * ELL_W * 4);
  int*    spill = (int*)alloc((size_t)nbk * SP_CAP * 4);
  float*  scsh  = (float*)alloc(6 * 64 * 4);
  // zero-init cluster: bcnt + psum + pcnt in one contiguous memset
  int*    bcnt  = (int*)alloc(NBMAX * 4);
  float*  psum  = (float*)alloc(64 * D * 4);
  float*  pcnt  = (float*)alloc(64 * 4);
  const size_t zbytes = ((char*)pcnt + 64 * 4) - (char*)bcnt;

  float* hout = (float*)d_out;
  float* hg   = (float*)d_out + (size_t)n * D;

  hipMemsetAsync(bcnt, 0, zbytes, stream);
  hipMemsetAsync(hbuf + (size_t)n * D, 0, D * 2, stream);   // zero row n (gather pad target)

  bucket_k<<<(e + CHUNK - 1) / CHUNK, 256, 0, stream>>>(src, dst, bcnt, pairs, e, nbk);
  bucket2csr_k<<<nbk, 256, 0, stream>>>(bcnt, pairs, rpdeg, dis, ell, spill, n);
  bnprep_k<<<1, 192, 0, stream>>>(b1, b2, b3, g1, be1, rm1, rv1, g2, be2, rm2, rv2, scsh);

  const int gemm_blocks = (n + GT_R - 1) / GT_R;
  const int agg_waves   = (n + 1) / 2;
  const int agg_blocks  = (agg_waves * 64 + 255) / 256;

  // layer 1
  gemm_k<float><<<gemm_blocks, 256, 0, stream>>>(x, W1, dis, hbuf, n);
  agg_k<true, __half><<<agg_blocks, 256, 0, stream>>>(hbuf, rpdeg, ell, spill, dis, scsh + 0 * 128, buf16, n);
  // layer 2
  gemm_k<__half><<<gemm_blocks, 256, 0, stream>>>(buf16, W2, dis, hbuf, n);
  agg_k<true, __half><<<agg_blocks, 256, 0, stream>>>(hbuf, rpdeg, ell, spill, dis, scsh + 1 * 128, buf16, n);
  // layer 3
  gemm_k<__half><<<gemm_blocks, 256, 0, stream>>>(buf16, W3, dis, hbuf, n);
  agg_k<false, float><<<agg_blocks, 256, 0, stream>>>(hbuf, rpdeg, ell, spill, dis, scsh + 2 * 128, hout, n);

  // pooling
  const int pool_waves = (n + 63) / 64;
  pool_k<<<(pool_waves * 64 + 255) / 256, 256, 0, stream>>>(hout, bat, psum, pcnt, n);
  pooldiv_k<<<(64 * D + 255) / 256, 256, 0, stream>>>(psum, pcnt, hg);
}

// Round 12
// 300.061 us; speedup vs baseline: 1.1756x; 1.1756x over previous
//
#include <hip/hip_runtime.h>
#include <hip/hip_fp16.h>

#define D 64
#define EPS 1e-5f

// CSR bucketing params: buckets of 512 consecutive dst nodes
#define BK_SHIFT 9
#define BK_W 512
#define NBMAX 256        // supports n up to 131072
#define BK_CAP 8192      // avg padded ~7040/bucket; margin ok
#define CHUNK 4096       // edges per bucket_k block (294 blocks > 256 CUs)

typedef _Float16 h8v __attribute__((ext_vector_type(8)));
typedef float f4v __attribute__((ext_vector_type(4)));

// ---------------- Phase A: bucketize edges; pack (src<<9 | dst_local) ----------------

__global__ __launch_bounds__(256) void bucket_k(const int* __restrict__ src,
                                                const int* __restrict__ dst,
                                                int* __restrict__ bcnt,
                                                int* __restrict__ pairs,
                                                int e, int nbk) {
  __shared__ int hcnt[NBMAX];
  __shared__ int hbase[NBMAX];
  const int t = threadIdx.x;
  const int e0 = blockIdx.x * CHUNK;
  const int e1 = min(e0 + CHUNK, e);
  for (int i = t; i < nbk; i += 256) hcnt[i] = 0;
  __syncthreads();
  for (int i = e0 + t; i < e1; i += 256)
    atomicAdd(&hcnt[dst[i] >> BK_SHIFT], 1);
  __syncthreads();
  for (int i = t; i < nbk; i += 256) {
    int c = hcnt[i];
    hbase[i] = c ? atomicAdd(&bcnt[i], c) : 0;
    hcnt[i] = 0;   // reuse as cursor
  }
  __syncthreads();
  for (int i = e0 + t; i < e1; i += 256) {
    int s = src[i], d = dst[i];
    int b = d >> BK_SHIFT;
    int r = hbase[b] + atomicAdd(&hcnt[b], 1);
    if (r < BK_CAP) pairs[(size_t)b * BK_CAP + r] = (s << BK_SHIFT) | (d & (BK_W - 1));
  }
}

// ---------------- Fused CSR: hist -> padded scan -> rpdeg/dis -> place -> col --------
// Node segments padded to multiples of 4 ints (agg int4-loads indices).
// stage pre-zeroed => pad slots hold index 0 (valid row; data predicated out in agg).

__global__ __launch_bounds__(256) void bucket2csr_k(const int* __restrict__ bcnt,
                                                    const int* __restrict__ pairs,
                                                    int2* __restrict__ rpdeg,
                                                    float* __restrict__ dis,
                                                    int* __restrict__ col, int n) {
  __shared__ int h[BK_W];
  __shared__ int cur[BK_W];
  __shared__ int s1[256], s2[256];
  __shared__ int stage[BK_CAP];
  const int b = blockIdx.x, t = threadIdx.x;
  const int base = b << BK_SHIFT;
  const int slab0 = b * BK_CAP;
  const int m = min(bcnt[b], BK_CAP);

  h[t] = 0; h[t + 256] = 0;
  for (int i = t; i < BK_CAP; i += 256) stage[i] = 0;
  __syncthreads();
  const int* p = pairs + (size_t)b * BK_CAP;
  for (int i = t; i < m; i += 256) atomicAdd(&h[p[i] & (BK_W - 1)], 1);
  __syncthreads();

  const int pc1 = (h[t] + 3) & ~3;         // padded counts (x4 alignment)
  const int pc2 = (h[t + 256] + 3) & ~3;
  s1[t] = pc1; s2[t] = pc2;
  __syncthreads();
  for (int off = 1; off < 256; off <<= 1) {
    int x1 = (t >= off) ? s1[t - off] : 0;
    int x2 = (t >= off) ? s2[t - off] : 0;
    __syncthreads();
    s1[t] += x1; s2[t] += x2;
    __syncthreads();
  }
  const int tot1 = s1[255];
  const int mpad = tot1 + s2[255];
  cur[t]       = s1[t] - pc1;
  cur[t + 256] = tot1 + s2[t] - pc2;
  {
    int n1 = base + t, n2 = base + t + 256;
    if (n1 < n) { rpdeg[n1] = make_int2(slab0 + cur[t], h[t]);
                  dis[n1] = rsqrtf((float)h[t] + 1.0f); }
    if (n2 < n) { rpdeg[n2] = make_int2(slab0 + cur[t + 256], h[t + 256]);
                  dis[n2] = rsqrtf((float)h[t + 256] + 1.0f); }
  }
  __syncthreads();

  for (int i = t; i < m; i += 256) {
    int pk = p[i];
    int r = atomicAdd(&cur[pk & (BK_W - 1)], 1);
    stage[r] = pk >> BK_SHIFT;
  }
  __syncthreads();
  const int mout = min(mpad + 16, BK_CAP);   // +16 zero tail for agg over-read
  for (int i = t; i < mout; i += 256) col[slab0 + i] = stage[i];
}

// ---------------- setup: zero scratch + BN fold + W->Wt fp16 transposes -------------
// Replaces bnprep + 2 memsets; one dispatch. Wt[j*64+k] = (fp16)W[k*64+j].

__global__ __launch_bounds__(256) void setup_k(const float* __restrict__ W1,
                                               const float* __restrict__ W2,
                                               const float* __restrict__ W3,
                                               const float* __restrict__ b1,
                                               const float* __restrict__ b2,
                                               const float* __restrict__ b3,
                                               const float* __restrict__ g1, const float* __restrict__ be1,
                                               const float* __restrict__ rm1, const float* __restrict__ rv1,
                                               const float* __restrict__ g2, const float* __restrict__ be2,
                                               const float* __restrict__ rm2, const float* __restrict__ rv2,
                                               _Float16* __restrict__ Wt1,
                                               _Float16* __restrict__ Wt2,
                                               _Float16* __restrict__ Wt3,
                                               float* __restrict__ scsh,
                                               int* __restrict__ zbase, int zwords,
                                               unsigned int* __restrict__ hzrow) {
  int gid = blockIdx.x * 256 + threadIdx.x;
  if (gid < zwords) { zbase[gid] = 0; return; }
  gid -= zwords;
  if (gid < 32) { hzrow[gid] = 0u; return; }   // zero fp16 row (gather pad target)
  gid -= 32;
  if (gid < 192) {
    int j = gid & 63, l = gid >> 6;
    float sc, sh;
    if (l == 0)      { sc = g1[j] * rsqrtf(rv1[j] + EPS); sh = (b1[j] - rm1[j]) * sc + be1[j]; }
    else if (l == 1) { sc = g2[j] * rsqrtf(rv2[j] + EPS); sh = (b2[j] - rm2[j]) * sc + be2[j]; }
    else             { sc = 1.0f;                          sh = b3[j]; }
    scsh[l * 128 + j] = sc;
    scsh[l * 128 + 64 + j] = sh;
    return;
  }
  gid -= 192;
  if (gid < 3 * 4096) {
    const int mat = gid >> 12, e = gid & 4095;
    const float* Wm = (mat == 0) ? W1 : (mat == 1) ? W2 : W3;
    _Float16* Wt    = (mat == 0) ? Wt1 : (mat == 1) ? Wt2 : Wt3;
    const int k = e >> 6, j = e & 63;
    Wt[j * 64 + k] = (_Float16)Wm[e];
  }
}

// ---------------- GEMM via MFMA: out[r] = dis[r] * (in[r] @ W), fp16 out -------------
// Wave = 16 rows x 64 cols: 4 col-group accs x 2 MFMAs (K=64). No LDS, no barriers.
// A-frag: A[m=lane&15][k=quad*8+j] (b128 from global; fp32 input converted in-reg).
// B-frag: Wt[col][k] contiguous 8 fp16 (global, L2-hot). C/D: col=lane&15,row=quad*4+reg.

template <typename InT>
__global__ __launch_bounds__(256) void gemm_k(const InT* __restrict__ in,
                                              const _Float16* __restrict__ Wt,
                                              const float* __restrict__ dis,
                                              __half* __restrict__ out, int nrows) {
  const int lane = threadIdx.x & 63;
  const int w    = threadIdx.x >> 6;
  const int t16  = lane & 15;
  const int q    = lane >> 4;
  const int rb   = blockIdx.x * 64 + w * 16;
  if (rb >= nrows) return;

  // B fragments: 4 col-groups x 2 K-halves
  h8v bf[4][2];
#pragma unroll
  for (int cg = 0; cg < 4; ++cg) {
    const _Float16* wp = Wt + (cg * 16 + t16) * 64 + q * 8;
    bf[cg][0] = *(const h8v*)(wp);
    bf[cg][1] = *(const h8v*)(wp + 32);
  }

  // A fragments (row clamped; garbage rows never stored)
  const int ar = min(rb + t16, nrows - 1);
  h8v a0, a1;
  if constexpr (sizeof(InT) == 2) {
    const _Float16* ap = (const _Float16*)in + (size_t)ar * D + q * 8;
    a0 = *(const h8v*)(ap);
    a1 = *(const h8v*)(ap + 32);
  } else {
    const float* ap = (const float*)in + (size_t)ar * D + q * 8;
    const float4 l0 = *(const float4*)(ap);
    const float4 h0 = *(const float4*)(ap + 4);
    const float4 l1 = *(const float4*)(ap + 32);
    const float4 h1 = *(const float4*)(ap + 36);
    a0[0] = (_Float16)l0.x; a0[1] = (_Float16)l0.y; a0[2] = (_Float16)l0.z; a0[3] = (_Float16)l0.w;
    a0[4] = (_Float16)h0.x; a0[5] = (_Float16)h0.y; a0[6] = (_Float16)h0.z; a0[7] = (_Float16)h0.w;
    a1[0] = (_Float16)l1.x; a1[1] = (_Float16)l1.y; a1[2] = (_Float16)l1.z; a1[3] = (_Float16)l1.w;
    a1[4] = (_Float16)h1.x; a1[5] = (_Float16)h1.y; a1[6] = (_Float16)h1.z; a1[7] = (_Float16)h1.w;
  }

  f4v acc0 = {0.f, 0.f, 0.f, 0.f};
  f4v acc1 = acc0, acc2 = acc0, acc3 = acc0;
  acc0 = __builtin_amdgcn_mfma_f32_16x16x32_f16(a0, bf[0][0], acc0, 0, 0, 0);
  acc1 = __builtin_amdgcn_mfma_f32_16x16x32_f16(a0, bf[1][0], acc1, 0, 0, 0);
  acc2 = __builtin_amdgcn_mfma_f32_16x16x32_f16(a0, bf[2][0], acc2, 0, 0, 0);
  acc3 = __builtin_amdgcn_mfma_f32_16x16x32_f16(a0, bf[3][0], acc3, 0, 0, 0);
  acc0 = __builtin_amdgcn_mfma_f32_16x16x32_f16(a1, bf[0][1], acc0, 0, 0, 0);
  acc1 = __builtin_amdgcn_mfma_f32_16x16x32_f16(a1, bf[1][1], acc1, 0, 0, 0);
  acc2 = __builtin_amdgcn_mfma_f32_16x16x32_f16(a1, bf[2][1], acc2, 0, 0, 0);
  acc3 = __builtin_amdgcn_mfma_f32_16x16x32_f16(a1, bf[3][1], acc3, 0, 0, 0);

  const float4 dv = *(const float4*)&dis[rb + q * 4];
  _Float16* oh = (_Float16*)out;
#pragma unroll
  for (int r = 0; r < 4; ++r) {
    const int row = rb + q * 4 + r;
    if (row < nrows) {
      const float dsc = (&dv.x)[r];
      _Float16* op = oh + (size_t)row * D + t16;
      op[0]  = (_Float16)(dsc * acc0[r]);
      op[16] = (_Float16)(dsc * acc1[r]);
      op[32] = (_Float16)(dsc * acc2[r]);
      op[48] = (_Float16)(dsc * acc3[r]);
    }
  }
}

// ---------------- Aggregation: 2 nodes/wave, interleaved chains (R10, known-good) ----

template <bool RELU, typename OutT>
__global__ __launch_bounds__(256) void agg_k(const __half* __restrict__ h2s,
                                             const int2* __restrict__ rpdeg,
                                             const int* __restrict__ col,
                                             const float* __restrict__ dis,
                                             const float* __restrict__ scsh,
                                             OutT* __restrict__ out, int n) {
  const int lane = threadIdx.x & 63;
  const int wv   = (blockIdx.x * blockDim.x + threadIdx.x) >> 6;
  const int n0   = __builtin_amdgcn_readfirstlane(wv * 2);
  if (n0 >= n) return;
  const bool v1 = (n0 + 1 < n);
  const int n1  = v1 ? n0 + 1 : n0;
  const int g  = lane >> 4;
  const int sl = lane & 15;
  const int jb = 4 * g;
  const uint2* __restrict__ h2v = (const uint2*)h2s;   // row = 16 x uint2

  const int4 rdp = *(const int4*)&rpdeg[n0];
  const int p0 = rdp.x, deg0 = rdp.y, p1 = rdp.z, deg1 = rdp.w;

  const uint2 self0 = h2v[(size_t)n0 * 16 + sl];
  const uint2 self1 = h2v[(size_t)n1 * 16 + sl];
  const int4 cc0 = *(const int4*)&col[p0 + jb];
  const int4 cc1 = *(const int4*)&col[p1 + jb];

  const __half2 zero2 = __floats2half2_rn(0.f, 0.f);
  const uint2 zz = make_uint2(0u, 0u);

  __half2 A0 = zero2, A1 = zero2, B0 = zero2, B1 = zero2;
  __half2 C0 = zero2, C1 = zero2, D0 = zero2, D1 = zero2;   // node0
  __half2 E0 = zero2, E1 = zero2, F0 = zero2, F1 = zero2;
  __half2 G0 = zero2, G1 = zero2, H0 = zero2, H1 = zero2;   // node1

  {  // first batch, both nodes
    uint2 r0 = h2v[(size_t)cc0.x * 16 + sl];
    uint2 r1 = h2v[(size_t)cc0.y * 16 + sl];
    uint2 r2 = h2v[(size_t)cc0.z * 16 + sl];
    uint2 r3 = h2v[(size_t)cc0.w * 16 + sl];
    uint2 q0 = h2v[(size_t)cc1.x * 16 + sl];
    uint2 q1 = h2v[(size_t)cc1.y * 16 + sl];
    uint2 q2 = h2v[(size_t)cc1.z * 16 + sl];
    uint2 q3 = h2v[(size_t)cc1.w * 16 + sl];
    r0 = (jb + 0 < deg0) ? r0 : zz;  r1 = (jb + 1 < deg0) ? r1 : zz;
    r2 = (jb + 2 < deg0) ? r2 : zz;  r3 = (jb + 3 < deg0) ? r3 : zz;
    q0 = (jb + 0 < deg1) ? q0 : zz;  q1 = (jb + 1 < deg1) ? q1 : zz;
    q2 = (jb + 2 < deg1) ? q2 : zz;  q3 = (jb + 3 < deg1) ? q3 : zz;
    A0 = __hadd2(A0, *(const __half2*)&r0.x); A1 = __hadd2(A1, *(const __half2*)&r0.y);
    B0 = __hadd2(B0, *(const __half2*)&r1.x); B1 = __hadd2(B1, *(const __half2*)&r1.y);
    C0 = __hadd2(C0, *(const __half2*)&r2.x); C1 = __hadd2(C1, *(const __half2*)&r2.y);
    D0 = __hadd2(D0, *(const __half2*)&r3.x); D1 = __hadd2(D1, *(const __half2*)&r3.y);
    E0 = __hadd2(E0, *(const __half2*)&q0.x); E1 = __hadd2(E1, *(const __half2*)&q0.y);
    F0 = __hadd2(F0, *(const __half2*)&q1.x); F1 = __hadd2(F1, *(const __half2*)&q1.y);
    G0 = __hadd2(G0, *(const __half2*)&q2.x); G1 = __hadd2(G1, *(const __half2*)&q2.y);
    H0 = __hadd2(H0, *(const __half2*)&q3.x); H1 = __hadd2(H1, *(const __half2*)&q3.y);
  }

  for (int e = 16; e < deg0; e += 16) {
    const int4 cc = *(const int4*)&col[p0 + e + jb];
    uint2 r0 = h2v[(size_t)cc.x * 16 + sl];
    uint2 r1 = h2v[(size_t)cc.y * 16 + sl];
    uint2 r2 = h2v[(size_t)cc.z * 16 + sl];
    uint2 r3 = h2v[(size_t)cc.w * 16 + sl];
    const int j = e + jb;
    r0 = (j + 0 < deg0) ? r0 : zz;  r1 = (j + 1 < deg0) ? r1 : zz;
    r2 = (j + 2 < deg0) ? r2 : zz;  r3 = (j + 3 < deg0) ? r3 : zz;
    A0 = __hadd2(A0, *(const __half2*)&r0.x); A1 = __hadd2(A1, *(const __half2*)&r0.y);
    B0 = __hadd2(B0, *(const __half2*)&r1.x); B1 = __hadd2(B1, *(const __half2*)&r1.y);
    C0 = __hadd2(C0, *(const __half2*)&r2.x); C1 = __hadd2(C1, *(const __half2*)&r2.y);
    D0 = __hadd2(D0, *(const __half2*)&r3.x); D1 = __hadd2(D1, *(const __half2*)&r3.y);
  }
  for (int e = 16; e < deg1; e += 16) {
    const int4 cc = *(const int4*)&col[p1 + e + jb];
    uint2 q0 = h2v[(size_t)cc.x * 16 + sl];
    uint2 q1 = h2v[(size_t)cc.y * 16 + sl];
    uint2 q2 = h2v[(size_t)cc.z * 16 + sl];
    uint2 q3 = h2v[(size_t)cc.w * 16 + sl];
    const int j = e + jb;
    q0 = (j + 0 < deg1) ? q0 : zz;  q1 = (j + 1 < deg1) ? q1 : zz;
    q2 = (j + 2 < deg1) ? q2 : zz;  q3 = (j + 3 < deg1) ? q3 : zz;
    E0 = __hadd2(E0, *(const __half2*)&q0.x); E1 = __hadd2(E1, *(const __half2*)&q0.y);
    F0 = __hadd2(F0, *(const __half2*)&q1.x); F1 = __hadd2(F1, *(const __half2*)&q1.y);
    G0 = __hadd2(G0, *(const __half2*)&q2.x); G1 = __hadd2(G1, *(const __half2*)&q2.y);
    H0 = __hadd2(H0, *(const __half2*)&q3.x); H1 = __hadd2(H1, *(const __half2*)&q3.y);
  }

  const float di0 = dis[n0];
  const float di1 = dis[n1];
  const float4 sc = *(const float4*)&scsh[4 * sl];
  const float4 sh = *(const float4*)&scsh[64 + 4 * sl];

  {
    const float2 a0 = __half22float2(A0), a1 = __half22float2(A1);
    const float2 b0 = __half22float2(B0), b1 = __half22float2(B1);
    const float2 c0 = __half22float2(C0), c1 = __half22float2(C1);
    const float2 d0 = __half22float2(D0), d1 = __half22float2(D1);
    float2 s0f = __half22float2(*(const __half2*)&self0.x);
    float2 s1f = __half22float2(*(const __half2*)&self0.y);
    float r0 = ((a0.x + b0.x) + (c0.x + d0.x)) + (g == 0 ? s0f.x : 0.f);
    float r1 = ((a0.y + b0.y) + (c0.y + d0.y)) + (g == 0 ? s0f.y : 0.f);
    float r2 = ((a1.x + b1.x) + (c1.x + d1.x)) + (g == 0 ? s1f.x : 0.f);
    float r3 = ((a1.y + b1.y) + (c1.y + d1.y)) + (g == 0 ? s1f.y : 0.f);
    r0 += __shfl_xor(r0, 16, 64); r1 += __shfl_xor(r1, 16, 64);
    r2 += __shfl_xor(r2, 16, 64); r3 += __shfl_xor(r3, 16, 64);
    r0 += __shfl_xor(r0, 32, 64); r1 += __shfl_xor(r1, 32, 64);
    r2 += __shfl_xor(r2, 32, 64); r3 += __shfl_xor(r3, 32, 64);
    float o0 = fmaf(di0 * r0, sc.x, sh.x);
    float o1 = fmaf(di0 * r1, sc.y, sh.y);
    float o2 = fmaf(di0 * r2, sc.z, sh.z);
    float o3 = fmaf(di0 * r3, sc.w, sh.w);
    if (RELU) {
      o0 = fmaxf(o0, 0.f); o1 = fmaxf(o1, 0.f);
      o2 = fmaxf(o2, 0.f); o3 = fmaxf(o3, 0.f);
    }
    if (g == 0) {
      if constexpr (sizeof(OutT) == 2) {
        union { __half2 h[2]; uint2 u; } v;
        v.h[0] = __floats2half2_rn(o0, o1);
        v.h[1] = __floats2half2_rn(o2, o3);
        *(uint2*)&out[(size_t)n0 * D + 4 * sl] = v.u;
      } else {
        *(float4*)&out[(size_t)n0 * D + 4 * sl] = make_float4(o0, o1, o2, o3);
      }
    }
  }
  {
    const float2 a0 = __half22float2(E0), a1 = __half22float2(E1);
    const float2 b0 = __half22float2(F0), b1 = __half22float2(F1);
    const float2 c0 = __half22float2(G0), c1 = __half22float2(G1);
    const float2 d0 = __half22float2(H0), d1 = __half22float2(H1);
    float2 s0f = __half22float2(*(const __half2*)&self1.x);
    float2 s1f = __half22float2(*(const __half2*)&self1.y);
    float r0 = ((a0.x + b0.x) + (c0.x + d0.x)) + (g == 0 ? s0f.x : 0.f);
    float r1 = ((a0.y + b0.y) + (c0.y + d0.y)) + (g == 0 ? s0f.y : 0.f);
    float r2 = ((a1.x + b1.x) + (c1.x + d1.x)) + (g == 0 ? s1f.x : 0.f);
    float r3 = ((a1.y + b1.y) + (c1.y + d1.y)) + (g == 0 ? s1f.y : 0.f);
    r0 += __shfl_xor(r0, 16, 64); r1 += __shfl_xor(r1, 16, 64);
    r2 += __shfl_xor(r2, 16, 64); r3 += __shfl_xor(r3, 16, 64);
    r0 += __shfl_xor(r0, 32, 64); r1 += __shfl_xor(r1, 32, 64);
    r2 += __shfl_xor(r2, 32, 64); r3 += __shfl_xor(r3, 32, 64);
    float o0 = fmaf(di1 * r0, sc.x, sh.x);
    float o1 = fmaf(di1 * r1, sc.y, sh.y);
    float o2 = fmaf(di1 * r2, sc.z, sh.z);
    float o3 = fmaf(di1 * r3, sc.w, sh.w);
    if (RELU) {
      o0 = fmaxf(o0, 0.f); o1 = fmaxf(o1, 0.f);
      o2 = fmaxf(o2, 0.f); o3 = fmaxf(o3, 0.f);
    }
    if (g == 0 && v1) {
      if constexpr (sizeof(OutT) == 2) {
        union { __half2 h[2]; uint2 u; } v;
        v.h[0] = __floats2half2_rn(o0, o1);
        v.h[1] = __floats2half2_rn(o2, o3);
        *(uint2*)&out[(size_t)n1 * D + 4 * sl] = v.u;
      } else {
        *(float4*)&out[(size_t)n1 * D + 4 * sl] = make_float4(o0, o1, o2, o3);
      }
    }
  }
}

// ---------------- Global mean pool (batch is sorted) ----------------

__global__ __launch_bounds__(256) void pool_k(const float* __restrict__ h,
                                              const int* __restrict__ batch,
                                              float* __restrict__ psum,
                                              float* __restrict__ pcnt, int n) {
  int lane  = threadIdx.x & 63;
  int wid   = __builtin_amdgcn_readfirstlane((blockIdx.x * blockDim.x + threadIdx.x) >> 6);
  int start = wid * 64;
  if (start >= n) return;
  int end = min(start + 64, n);
  int cur = batch[start];
  float sum = 0.f;
  int run = 0;
  for (int i = start; i < end; ++i) {
    int g = batch[i];
    if (g != cur) {
      atomicAdd(&psum[cur * D + lane], sum);
      if (lane == 0) atomicAdd(&pcnt[cur], (float)run);
      sum = 0.f; run = 0; cur = g;
    }
    sum += h[(size_t)i * D + lane];
    run += 1;
  }
  atomicAdd(&psum[cur * D + lane], sum);
  if (lane == 0) atomicAdd(&pcnt[cur], (float)run);
}

__global__ void pooldiv_k(const float* __restrict__ psum, const float* __restrict__ pcnt,
                          float* __restrict__ hg) {
  int t = blockIdx.x * blockDim.x + threadIdx.x;
  if (t < 64 * D) hg[t] = psum[t] / fmaxf(pcnt[t >> 6], 1.0f);
}

// ---------------- launcher ----------------

extern "C" void kernel_launch(void* const* d_in, const int* in_sizes, int n_in,
                              void* d_out, int out_size, void* d_ws, size_t ws_size,
                              hipStream_t stream) {
  const float* x   = (const float*)d_in[0];
  const int*   ei  = (const int*)d_in[1];
  const int*   bat = (const int*)d_in[2];
  const float* W1  = (const float*)d_in[3];
  const float* W2  = (const float*)d_in[4];
  const float* W3  = (const float*)d_in[5];
  const float* b1  = (const float*)d_in[6];
  const float* b2  = (const float*)d_in[7];
  const float* b3  = (const float*)d_in[8];
  const float* g1  = (const float*)d_in[9];
  const float* be1 = (const float*)d_in[10];
  const float* rm1 = (const float*)d_in[11];
  const float* rv1 = (const float*)d_in[12];
  const float* g2  = (const float*)d_in[13];
  const float* be2 = (const float*)d_in[14];
  const float* rm2 = (const float*)d_in[15];
  const float* rv2 = (const float*)d_in[16];

  const int n = in_sizes[0] / D;   // 100000
  const int e = in_sizes[1] / 2;   // 1200000
  const int* src = ei;
  const int* dst = ei + e;
  const int nbk = (n + BK_W - 1) >> BK_SHIFT;   // 196

  char* ws = (char*)d_ws;
  size_t off = 0;
  auto alloc = [&](size_t bytes) -> void* {
    void* p = ws + off;
    off = (off + bytes + 255) & ~(size_t)255;
    return p;
  };
  __half*   buf16 = (__half*)alloc((size_t)n * D * 2);        // agg fp16 out (layers 1,2)
  int*      pairs = (int*)alloc((size_t)NBMAX * BK_CAP * 4);  // bucket slabs
  __half*   hbuf  = (__half*)alloc((size_t)(n + 1) * D * 2);  // gemm fp16 out + zero row n
  int2*     rpdeg = (int2*)alloc((size_t)(n + 1) * 8);
  float*    dis   = (float*)alloc((size_t)(n + 16) * 4);      // +16 pad for gemm dv reads
  int*      col   = (int*)alloc((size_t)NBMAX * BK_CAP * 4);  // CSR in padded slabs
  float*    scsh  = (float*)alloc(6 * 64 * 4);
  _Float16* Wt1   = (_Float16*)alloc(4096 * 2);
  _Float16* Wt2   = (_Float16*)alloc(4096 * 2);
  _Float16* Wt3   = (_Float16*)alloc(4096 * 2);
  // zero-init cluster: bcnt + psum + pcnt contiguous (each 256B-aligned size)
  int*      bcnt  = (int*)alloc(NBMAX * 4);
  float*    psum  = (float*)alloc(64 * D * 4);
  float*    pcnt  = (float*)alloc(64 * 4);
  const int zwords = (int)((((char*)pcnt + 64 * 4) - (char*)bcnt) / 4);

  float* hout = (float*)d_out;
  float* hg   = (float*)d_out + (size_t)n * D;

  // setup: zeros + BN fold + Wt transposes (replaces bnprep + 2 memsets)
  const int setup_items = zwords + 32 + 192 + 3 * 4096;
  setup_k<<<(setup_items + 255) / 256, 256, 0, stream>>>(
      W1, W2, W3, b1, b2, b3, g1, be1, rm1, rv1, g2, be2, rm2, rv2,
      Wt1, Wt2, Wt3, scsh, bcnt, zwords, (unsigned int*)(hbuf + (size_t)n * D));

  bucket_k<<<(e + CHUNK - 1) / CHUNK, 256, 0, stream>>>(src, dst, bcnt, pairs, e, nbk);
  bucket2csr_k<<<nbk, 256, 0, stream>>>(bcnt, pairs, rpdeg, dis, col, n);

  const int gemm_blocks = (n + 63) / 64;
  const int agg_waves   = (n + 1) / 2;
  const int agg_blocks  = (agg_waves * 64 + 255) / 256;

  // layer 1
  gemm_k<float><<<gemm_blocks, 256, 0, stream>>>(x, Wt1, dis, hbuf, n);
  agg_k<true, __half><<<agg_blocks, 256, 0, stream>>>(hbuf, rpdeg, col, dis, scsh + 0 * 128, buf16, n);
  // layer 2
  gemm_k<__half><<<gemm_blocks, 256, 0, stream>>>(buf16, Wt2, dis, hbuf, n);
  agg_k<true, __half><<<agg_blocks, 256, 0, stream>>>(hbuf, rpdeg, col, dis, scsh + 1 * 128, buf16, n);
  // layer 3
  gemm_k<__half><<<gemm_blocks, 256, 0, stream>>>(buf16, Wt3, dis, hbuf, n);
  agg_k<false, float><<<agg_blocks, 256, 0, stream>>>(hbuf, rpdeg, col, dis, scsh + 2 * 128, hout, n);

  // pooling
  const int pool_waves = (n + 63) / 64;
  pool_k<<<(pool_waves * 64 + 255) / 256, 256, 0, stream>>>(hout, bat, psum, pcnt, n);
  pooldiv_k<<<(64 * D + 255) / 256, 256, 0, stream>>>(psum, pcnt, hg);
}

// Round 13
// 297.433 us; speedup vs baseline: 1.1860x; 1.0088x over previous
//
#include <hip/hip_runtime.h>
#include <hip/hip_fp16.h>

#define D 64
#define EPS 1e-5f

// CSR bucketing params: buckets of 512 consecutive dst nodes
#define BK_SHIFT 9
#define BK_W 512
#define NBMAX 256        // supports n up to 131072
#define BK_CAP 8192      // avg padded ~7040/bucket; margin ok
#define CHUNK 4096       // edges per bucket_k block (294 blocks > 256 CUs)

typedef _Float16 h8v __attribute__((ext_vector_type(8)));
typedef float f4v __attribute__((ext_vector_type(4)));

// ---------------- Phase A: bucketize edges; pack (src<<9 | dst_local) ----------------

__global__ __launch_bounds__(256) void bucket_k(const int* __restrict__ src,
                                                const int* __restrict__ dst,
                                                int* __restrict__ bcnt,
                                                int* __restrict__ pairs,
                                                int e, int nbk) {
  __shared__ int hcnt[NBMAX];
  __shared__ int hbase[NBMAX];
  const int t = threadIdx.x;
  const int e0 = blockIdx.x * CHUNK;
  const int e1 = min(e0 + CHUNK, e);
  for (int i = t; i < nbk; i += 256) hcnt[i] = 0;
  __syncthreads();
  for (int i = e0 + t; i < e1; i += 256)
    atomicAdd(&hcnt[dst[i] >> BK_SHIFT], 1);
  __syncthreads();
  for (int i = t; i < nbk; i += 256) {
    int c = hcnt[i];
    hbase[i] = c ? atomicAdd(&bcnt[i], c) : 0;
    hcnt[i] = 0;   // reuse as cursor
  }
  __syncthreads();
  for (int i = e0 + t; i < e1; i += 256) {
    int s = src[i], d = dst[i];
    int b = d >> BK_SHIFT;
    int r = hbase[b] + atomicAdd(&hcnt[b], 1);
    if (r < BK_CAP) pairs[(size_t)b * BK_CAP + r] = (s << BK_SHIFT) | (d & (BK_W - 1));
  }
}

// ---------------- Fused CSR: hist -> padded scan -> rpdeg/dis -> place -> col --------

__global__ __launch_bounds__(256) void bucket2csr_k(const int* __restrict__ bcnt,
                                                    const int* __restrict__ pairs,
                                                    int2* __restrict__ rpdeg,
                                                    float* __restrict__ dis,
                                                    int* __restrict__ col, int n) {
  __shared__ int h[BK_W];
  __shared__ int cur[BK_W];
  __shared__ int s1[256], s2[256];
  __shared__ int stage[BK_CAP];
  const int b = blockIdx.x, t = threadIdx.x;
  const int base = b << BK_SHIFT;
  const int slab0 = b * BK_CAP;
  const int m = min(bcnt[b], BK_CAP);

  h[t] = 0; h[t + 256] = 0;
  for (int i = t; i < BK_CAP; i += 256) stage[i] = 0;
  __syncthreads();
  const int* p = pairs + (size_t)b * BK_CAP;
  for (int i = t; i < m; i += 256) atomicAdd(&h[p[i] & (BK_W - 1)], 1);
  __syncthreads();

  const int pc1 = (h[t] + 3) & ~3;
  const int pc2 = (h[t + 256] + 3) & ~3;
  s1[t] = pc1; s2[t] = pc2;
  __syncthreads();
  for (int off = 1; off < 256; off <<= 1) {
    int x1 = (t >= off) ? s1[t - off] : 0;
    int x2 = (t >= off) ? s2[t - off] : 0;
    __syncthreads();
    s1[t] += x1; s2[t] += x2;
    __syncthreads();
  }
  const int tot1 = s1[255];
  const int mpad = tot1 + s2[255];
  cur[t]       = s1[t] - pc1;
  cur[t + 256] = tot1 + s2[t] - pc2;
  {
    int n1 = base + t, n2 = base + t + 256;
    if (n1 < n) { rpdeg[n1] = make_int2(slab0 + cur[t], h[t]);
                  dis[n1] = rsqrtf((float)h[t] + 1.0f); }
    if (n2 < n) { rpdeg[n2] = make_int2(slab0 + cur[t + 256], h[t + 256]);
                  dis[n2] = rsqrtf((float)h[t + 256] + 1.0f); }
  }
  __syncthreads();

  for (int i = t; i < m; i += 256) {
    int pk = p[i];
    int r = atomicAdd(&cur[pk & (BK_W - 1)], 1);
    stage[r] = pk >> BK_SHIFT;
  }
  __syncthreads();
  const int mout = min(mpad + 16, BK_CAP);
  for (int i = t; i < mout; i += 256) col[slab0 + i] = stage[i];
}

// ---------------- setup: zero scratch + BN fold + W->Wt fp16 transposes -------------

__global__ __launch_bounds__(256) void setup_k(const float* __restrict__ W1,
                                               const float* __restrict__ W2,
                                               const float* __restrict__ W3,
                                               const float* __restrict__ b1,
                                               const float* __restrict__ b2,
                                               const float* __restrict__ b3,
                                               const float* __restrict__ g1, const float* __restrict__ be1,
                                               const float* __restrict__ rm1, const float* __restrict__ rv1,
                                               const float* __restrict__ g2, const float* __restrict__ be2,
                                               const float* __restrict__ rm2, const float* __restrict__ rv2,
                                               _Float16* __restrict__ Wt1,
                                               _Float16* __restrict__ Wt2,
                                               _Float16* __restrict__ Wt3,
                                               float* __restrict__ scsh,
                                               int* __restrict__ zbase, int zwords,
                                               unsigned int* __restrict__ hzrow) {
  int gid = blockIdx.x * 256 + threadIdx.x;
  if (gid < zwords) { zbase[gid] = 0; return; }
  gid -= zwords;
  if (gid < 32) { hzrow[gid] = 0u; return; }
  gid -= 32;
  if (gid < 192) {
    int j = gid & 63, l = gid >> 6;
    float sc, sh;
    if (l == 0)      { sc = g1[j] * rsqrtf(rv1[j] + EPS); sh = (b1[j] - rm1[j]) * sc + be1[j]; }
    else if (l == 1) { sc = g2[j] * rsqrtf(rv2[j] + EPS); sh = (b2[j] - rm2[j]) * sc + be2[j]; }
    else             { sc = 1.0f;                          sh = b3[j]; }
    scsh[l * 128 + j] = sc;
    scsh[l * 128 + 64 + j] = sh;
    return;
  }
  gid -= 192;
  if (gid < 3 * 4096) {
    const int mat = gid >> 12, e = gid & 4095;
    const float* Wm = (mat == 0) ? W1 : (mat == 1) ? W2 : W3;
    _Float16* Wt    = (mat == 0) ? Wt1 : (mat == 1) ? Wt2 : Wt3;
    const int k = e >> 6, j = e & 63;
    Wt[j * 64 + k] = (_Float16)Wm[e];
  }
}

// ---------------- GEMM via MFMA (R12, known-good) ----------------

template <typename InT>
__global__ __launch_bounds__(256) void gemm_k(const InT* __restrict__ in,
                                              const _Float16* __restrict__ Wt,
                                              const float* __restrict__ dis,
                                              __half* __restrict__ out, int nrows) {
  const int lane = threadIdx.x & 63;
  const int w    = threadIdx.x >> 6;
  const int t16  = lane & 15;
  const int q    = lane >> 4;
  const int rb   = blockIdx.x * 64 + w * 16;
  if (rb >= nrows) return;

  h8v bf[4][2];
#pragma unroll
  for (int cg = 0; cg < 4; ++cg) {
    const _Float16* wp = Wt + (cg * 16 + t16) * 64 + q * 8;
    bf[cg][0] = *(const h8v*)(wp);
    bf[cg][1] = *(const h8v*)(wp + 32);
  }

  const int ar = min(rb + t16, nrows - 1);
  h8v a0, a1;
  if constexpr (sizeof(InT) == 2) {
    const _Float16* ap = (const _Float16*)in + (size_t)ar * D + q * 8;
    a0 = *(const h8v*)(ap);
    a1 = *(const h8v*)(ap + 32);
  } else {
    const float* ap = (const float*)in + (size_t)ar * D + q * 8;
    const float4 l0 = *(const float4*)(ap);
    const float4 h0 = *(const float4*)(ap + 4);
    const float4 l1 = *(const float4*)(ap + 32);
    const float4 h1 = *(const float4*)(ap + 36);
    a0[0] = (_Float16)l0.x; a0[1] = (_Float16)l0.y; a0[2] = (_Float16)l0.z; a0[3] = (_Float16)l0.w;
    a0[4] = (_Float16)h0.x; a0[5] = (_Float16)h0.y; a0[6] = (_Float16)h0.z; a0[7] = (_Float16)h0.w;
    a1[0] = (_Float16)l1.x; a1[1] = (_Float16)l1.y; a1[2] = (_Float16)l1.z; a1[3] = (_Float16)l1.w;
    a1[4] = (_Float16)h1.x; a1[5] = (_Float16)h1.y; a1[6] = (_Float16)h1.z; a1[7] = (_Float16)h1.w;
  }

  f4v acc0 = {0.f, 0.f, 0.f, 0.f};
  f4v acc1 = acc0, acc2 = acc0, acc3 = acc0;
  acc0 = __builtin_amdgcn_mfma_f32_16x16x32_f16(a0, bf[0][0], acc0, 0, 0, 0);
  acc1 = __builtin_amdgcn_mfma_f32_16x16x32_f16(a0, bf[1][0], acc1, 0, 0, 0);
  acc2 = __builtin_amdgcn_mfma_f32_16x16x32_f16(a0, bf[2][0], acc2, 0, 0, 0);
  acc3 = __builtin_amdgcn_mfma_f32_16x16x32_f16(a0, bf[3][0], acc3, 0, 0, 0);
  acc0 = __builtin_amdgcn_mfma_f32_16x16x32_f16(a1, bf[0][1], acc0, 0, 0, 0);
  acc1 = __builtin_amdgcn_mfma_f32_16x16x32_f16(a1, bf[1][1], acc1, 0, 0, 0);
  acc2 = __builtin_amdgcn_mfma_f32_16x16x32_f16(a1, bf[2][1], acc2, 0, 0, 0);
  acc3 = __builtin_amdgcn_mfma_f32_16x16x32_f16(a1, bf[3][1], acc3, 0, 0, 0);

  const float4 dv = *(const float4*)&dis[rb + q * 4];
  _Float16* oh = (_Float16*)out;
#pragma unroll
  for (int r = 0; r < 4; ++r) {
    const int row = rb + q * 4 + r;
    if (row < nrows) {
      const float dsc = (&dv.x)[r];
      _Float16* op = oh + (size_t)row * D + t16;
      op[0]  = (_Float16)(dsc * acc0[r]);
      op[16] = (_Float16)(dsc * acc1[r]);
      op[32] = (_Float16)(dsc * acc2[r]);
      op[48] = (_Float16)(dsc * acc3[r]);
    }
  }
}

// ---------------- Aggregation: 4 nodes/wave, interleaved chains ----------------
// Wave w owns nodes 4w..4w+3. All 4 nodes' rpdeg, self rows, col int4s, and
// first-batch gathers (16 lines) issue together -> ~2x in-flight vs R10.
// Per-node accs compressed to 4 half2 (add chains <=2 per batch, fp16-safe).

template <bool RELU, typename OutT>
__global__ __launch_bounds__(256) void agg_k(const __half* __restrict__ h2s,
                                             const int2* __restrict__ rpdeg,
                                             const int* __restrict__ col,
                                             const float* __restrict__ dis,
                                             const float* __restrict__ scsh,
                                             OutT* __restrict__ out, int n) {
  const int lane = threadIdx.x & 63;
  const int wv   = (blockIdx.x * blockDim.x + threadIdx.x) >> 6;
  const int nb   = __builtin_amdgcn_readfirstlane(wv * 4);
  if (nb >= n) return;
  const int g  = lane >> 4;
  const int sl = lane & 15;
  const int jb = 4 * g;
  const uint2* __restrict__ h2v = (const uint2*)h2s;   // row = 16 x uint2

  int nd[4], p[4], dg[4];
#pragma unroll
  for (int i = 0; i < 4; ++i) nd[i] = min(nb + i, n - 1);
#pragma unroll
  for (int i = 0; i < 4; ++i) { int2 rd = rpdeg[nd[i]]; p[i] = rd.x; dg[i] = rd.y; }

  uint2 self[4];
  int4  cc[4];
#pragma unroll
  for (int i = 0; i < 4; ++i) {
    self[i] = h2v[(size_t)nd[i] * 16 + sl];
    cc[i]   = *(const int4*)&col[p[i] + jb];
  }

  const __half2 zero2 = __floats2half2_rn(0.f, 0.f);
  const uint2 zz = make_uint2(0u, 0u);
  __half2 acc[4][4];
#pragma unroll
  for (int i = 0; i < 4; ++i)
#pragma unroll
    for (int s = 0; s < 4; ++s) acc[i][s] = zero2;

  // first batch, all 4 nodes (16 independent gathers)
#pragma unroll
  for (int i = 0; i < 4; ++i) {
    uint2 r0 = h2v[(size_t)cc[i].x * 16 + sl];
    uint2 r1 = h2v[(size_t)cc[i].y * 16 + sl];
    uint2 r2 = h2v[(size_t)cc[i].z * 16 + sl];
    uint2 r3 = h2v[(size_t)cc[i].w * 16 + sl];
    r0 = (jb + 0 < dg[i]) ? r0 : zz;  r1 = (jb + 1 < dg[i]) ? r1 : zz;
    r2 = (jb + 2 < dg[i]) ? r2 : zz;  r3 = (jb + 3 < dg[i]) ? r3 : zz;
    acc[i][0] = __hadd2(acc[i][0], *(const __half2*)&r0.x);
    acc[i][1] = __hadd2(acc[i][1], *(const __half2*)&r0.y);
    acc[i][2] = __hadd2(acc[i][2], *(const __half2*)&r1.x);
    acc[i][3] = __hadd2(acc[i][3], *(const __half2*)&r1.y);
    acc[i][0] = __hadd2(acc[i][0], *(const __half2*)&r2.x);
    acc[i][1] = __hadd2(acc[i][1], *(const __half2*)&r2.y);
    acc[i][2] = __hadd2(acc[i][2], *(const __half2*)&r3.x);
    acc[i][3] = __hadd2(acc[i][3], *(const __half2*)&r3.y);
  }

  // tails (deg > 16), per node, wave-uniform trip counts
#pragma unroll
  for (int i = 0; i < 4; ++i) {
    for (int e = 16; e < dg[i]; e += 16) {
      const int4 c2 = *(const int4*)&col[p[i] + e + jb];
      uint2 r0 = h2v[(size_t)c2.x * 16 + sl];
      uint2 r1 = h2v[(size_t)c2.y * 16 + sl];
      uint2 r2 = h2v[(size_t)c2.z * 16 + sl];
      uint2 r3 = h2v[(size_t)c2.w * 16 + sl];
      const int j = e + jb;
      r0 = (j + 0 < dg[i]) ? r0 : zz;  r1 = (j + 1 < dg[i]) ? r1 : zz;
      r2 = (j + 2 < dg[i]) ? r2 : zz;  r3 = (j + 3 < dg[i]) ? r3 : zz;
      acc[i][0] = __hadd2(acc[i][0], *(const __half2*)&r0.x);
      acc[i][1] = __hadd2(acc[i][1], *(const __half2*)&r0.y);
      acc[i][2] = __hadd2(acc[i][2], *(const __half2*)&r1.x);
      acc[i][3] = __hadd2(acc[i][3], *(const __half2*)&r1.y);
      acc[i][0] = __hadd2(acc[i][0], *(const __half2*)&r2.x);
      acc[i][1] = __hadd2(acc[i][1], *(const __half2*)&r2.y);
      acc[i][2] = __hadd2(acc[i][2], *(const __half2*)&r3.x);
      acc[i][3] = __hadd2(acc[i][3], *(const __half2*)&r3.y);
    }
  }

  const float4 sc = *(const float4*)&scsh[4 * sl];
  const float4 sh = *(const float4*)&scsh[64 + 4 * sl];

#pragma unroll
  for (int i = 0; i < 4; ++i) {
    const float2 a0 = __half22float2(acc[i][0]);
    const float2 a1 = __half22float2(acc[i][1]);
    const float2 a2 = __half22float2(acc[i][2]);
    const float2 a3 = __half22float2(acc[i][3]);
    const float2 s0f = __half22float2(*(const __half2*)&self[i].x);
    const float2 s1f = __half22float2(*(const __half2*)&self[i].y);
    float r0 = (a0.x + a2.x) + (g == 0 ? s0f.x : 0.f);
    float r1 = (a0.y + a2.y) + (g == 0 ? s0f.y : 0.f);
    float r2 = (a1.x + a3.x) + (g == 0 ? s1f.x : 0.f);
    float r3 = (a1.y + a3.y) + (g == 0 ? s1f.y : 0.f);
    r0 += __shfl_xor(r0, 16, 64); r1 += __shfl_xor(r1, 16, 64);
    r2 += __shfl_xor(r2, 16, 64); r3 += __shfl_xor(r3, 16, 64);
    r0 += __shfl_xor(r0, 32, 64); r1 += __shfl_xor(r1, 32, 64);
    r2 += __shfl_xor(r2, 32, 64); r3 += __shfl_xor(r3, 32, 64);
    const float di = dis[nd[i]];
    float o0 = fmaf(di * r0, sc.x, sh.x);
    float o1 = fmaf(di * r1, sc.y, sh.y);
    float o2 = fmaf(di * r2, sc.z, sh.z);
    float o3 = fmaf(di * r3, sc.w, sh.w);
    if (RELU) {
      o0 = fmaxf(o0, 0.f); o1 = fmaxf(o1, 0.f);
      o2 = fmaxf(o2, 0.f); o3 = fmaxf(o3, 0.f);
    }
    if (g == 0 && nb + i < n) {
      if constexpr (sizeof(OutT) == 2) {
        union { __half2 h[2]; uint2 u; } v;
        v.h[0] = __floats2half2_rn(o0, o1);
        v.h[1] = __floats2half2_rn(o2, o3);
        *(uint2*)&out[(size_t)nd[i] * D + 4 * sl] = v.u;
      } else {
        *(float4*)&out[(size_t)nd[i] * D + 4 * sl] = make_float4(o0, o1, o2, o3);
      }
    }
  }
}

// ---------------- Global mean pool (batch is sorted) ----------------

__global__ __launch_bounds__(256) void pool_k(const float* __restrict__ h,
                                              const int* __restrict__ batch,
                                              float* __restrict__ psum,
                                              float* __restrict__ pcnt, int n) {
  int lane  = threadIdx.x & 63;
  int wid   = __builtin_amdgcn_readfirstlane((blockIdx.x * blockDim.x + threadIdx.x) >> 6);
  int start = wid * 64;
  if (start >= n) return;
  int end = min(start + 64, n);
  int cur = batch[start];
  float sum = 0.f;
  int run = 0;
  for (int i = start; i < end; ++i) {
    int g = batch[i];
    if (g != cur) {
      atomicAdd(&psum[cur * D + lane], sum);
      if (lane == 0) atomicAdd(&pcnt[cur], (float)run);
      sum = 0.f; run = 0; cur = g;
    }
    sum += h[(size_t)i * D + lane];
    run += 1;
  }
  atomicAdd(&psum[cur * D + lane], sum);
  if (lane == 0) atomicAdd(&pcnt[cur], (float)run);
}

__global__ void pooldiv_k(const float* __restrict__ psum, const float* __restrict__ pcnt,
                          float* __restrict__ hg) {
  int t = blockIdx.x * blockDim.x + threadIdx.x;
  if (t < 64 * D) hg[t] = psum[t] / fmaxf(pcnt[t >> 6], 1.0f);
}

// ---------------- launcher ----------------

extern "C" void kernel_launch(void* const* d_in, const int* in_sizes, int n_in,
                              void* d_out, int out_size, void* d_ws, size_t ws_size,
                              hipStream_t stream) {
  const float* x   = (const float*)d_in[0];
  const int*   ei  = (const int*)d_in[1];
  const int*   bat = (const int*)d_in[2];
  const float* W1  = (const float*)d_in[3];
  const float* W2  = (const float*)d_in[4];
  const float* W3  = (const float*)d_in[5];
  const float* b1  = (const float*)d_in[6];
  const float* b2  = (const float*)d_in[7];
  const float* b3  = (const float*)d_in[8];
  const float* g1  = (const float*)d_in[9];
  const float* be1 = (const float*)d_in[10];
  const float* rm1 = (const float*)d_in[11];
  const float* rv1 = (const float*)d_in[12];
  const float* g2  = (const float*)d_in[13];
  const float* be2 = (const float*)d_in[14];
  const float* rm2 = (const float*)d_in[15];
  const float* rv2 = (const float*)d_in[16];

  const int n = in_sizes[0] / D;   // 100000
  const int e = in_sizes[1] / 2;   // 1200000
  const int* src = ei;
  const int* dst = ei + e;
  const int nbk = (n + BK_W - 1) >> BK_SHIFT;   // 196

  char* ws = (char*)d_ws;
  size_t off = 0;
  auto alloc = [&](size_t bytes) -> void* {
    void* p = ws + off;
    off = (off + bytes + 255) & ~(size_t)255;
    return p;
  };
  __half*   buf16 = (__half*)alloc((size_t)n * D * 2);        // agg fp16 out (layers 1,2)
  int*      pairs = (int*)alloc((size_t)NBMAX * BK_CAP * 4);  // bucket slabs
  __half*   hbuf  = (__half*)alloc((size_t)(n + 1) * D * 2);  // gemm fp16 out + zero row n
  int2*     rpdeg = (int2*)alloc((size_t)(n + 1) * 8);
  float*    dis   = (float*)alloc((size_t)(n + 16) * 4);      // +16 pad for gemm dv reads
  int*      col   = (int*)alloc((size_t)NBMAX * BK_CAP * 4);  // CSR in padded slabs
  float*    scsh  = (float*)alloc(6 * 64 * 4);
  _Float16* Wt1   = (_Float16*)alloc(4096 * 2);
  _Float16* Wt2   = (_Float16*)alloc(4096 * 2);
  _Float16* Wt3   = (_Float16*)alloc(4096 * 2);
  // zero-init cluster: bcnt + psum + pcnt contiguous
  int*      bcnt  = (int*)alloc(NBMAX * 4);
  float*    psum  = (float*)alloc(64 * D * 4);
  float*    pcnt  = (float*)alloc(64 * 4);
  const int zwords = (int)((((char*)pcnt + 64 * 4) - (char*)bcnt) / 4);

  float* hout = (float*)d_out;
  float* hg   = (float*)d_out + (size_t)n * D;

  const int setup_items = zwords + 32 + 192 + 3 * 4096;
  setup_k<<<(setup_items + 255) / 256, 256, 0, stream>>>(
      W1, W2, W3, b1, b2, b3, g1, be1, rm1, rv1, g2, be2, rm2, rv2,
      Wt1, Wt2, Wt3, scsh, bcnt, zwords, (unsigned int*)(hbuf + (size_t)n * D));

  bucket_k<<<(e + CHUNK - 1) / CHUNK, 256, 0, stream>>>(src, dst, bcnt, pairs, e, nbk);
  bucket2csr_k<<<nbk, 256, 0, stream>>>(bcnt, pairs, rpdeg, dis, col, n);

  const int gemm_blocks = (n + 63) / 64;
  const int agg_waves   = (n + 3) / 4;
  const int agg_blocks  = (agg_waves * 64 + 255) / 256;

  // layer 1
  gemm_k<float><<<gemm_blocks, 256, 0, stream>>>(x, Wt1, dis, hbuf, n);
  agg_k<true, __half><<<agg_blocks, 256, 0, stream>>>(hbuf, rpdeg, col, dis, scsh + 0 * 128, buf16, n);
  // layer 2
  gemm_k<__half><<<gemm_blocks, 256, 0, stream>>>(buf16, Wt2, dis, hbuf, n);
  agg_k<true, __half><<<agg_blocks, 256, 0, stream>>>(hbuf, rpdeg, col, dis, scsh + 1 * 128, buf16, n);
  // layer 3
  gemm_k<__half><<<gemm_blocks, 256, 0, stream>>>(buf16, Wt3, dis, hbuf, n);
  agg_k<false, float><<<agg_blocks, 256, 0, stream>>>(hbuf, rpdeg, col, dis, scsh + 2 * 128, hout, n);

  // pooling
  const int pool_waves = (n + 63) / 64;
  pool_k<<<(pool_waves * 64 + 255) / 256, 256, 0, stream>>>(hout, bat, psum, pcnt, n);
  pooldiv_k<<<(64 * D + 255) / 256, 256, 0, stream>>>(psum, pcnt, hg);
}